// Round 18
// baseline (98.661 us; speedup 1.0000x reference)
//
#include <hip/hip_runtime.h>

#define SEQ  2048
#define DH   64
#define QBLK 128         // q rows per q-block
#define KBLK 64          // k/v rows per tile
#define NQB  (SEQ/QBLK)  // 16
#define NTIL (SEQ/KBLK)  // 32 tiles per bh
#define THR  11.5f       // defer-max threshold (log2 domain)
#define KPAT(r) ((((r)&3)) + 8*((r)>>2))   // 32x32 C/D row pattern
#define WS_NEEDED ((size_t)2 * 64 * SEQ * DH * 2)   // K+V bf16 images = 33.5 MB

typedef short bf16x8 __attribute__((ext_vector_type(8)));   // 8 bf16 bits = 4 VGPRs
typedef float f32x16 __attribute__((ext_vector_type(16)));

union V4U { unsigned int w[4]; bf16x8 v; };

__device__ __forceinline__ short bfbits(float f) {
    unsigned int u = __float_as_uint(f);
    u += 0x7fff + ((u >> 16) & 1);
    return (short)(u >> 16);
}
__device__ __forceinline__ unsigned int cvtpk(float lo, float hi) {
    unsigned int r;
    asm("v_cvt_pk_bf16_f32 %0, %1, %2" : "=v"(r) : "v"(lo), "v"(hi));
    return r;
}
// swizzled short-index into a [rows][64] bf16 LDS tile (prep transpose only)
__device__ __forceinline__ int swz(int row, int col) {
    return row * 64 + (col ^ ((row & 7) << 3));
}

// ================= pre-pass: K/V -> bf16 FRAGMENT-MAJOR tile images =================
// K tile image layout (4096 shorts): idx = dc*1024 + h*512 + sub*256 + row32*8 + j
// V tile image layout: idx = kt*1024 + h*512 + d*8 + j  (d = 0..63 output dim)
__global__ __launch_bounds__(256) void prep_kv(const float* __restrict__ Kg,
                                               const float* __restrict__ Vg,
                                               short* __restrict__ Kimg,
                                               short* __restrict__ Vimg) {
    __shared__ __align__(16) short Vt[64 * 64];   // swizzled [d][k] transpose buffer
    const int tid = threadIdx.x;
    const int t   = blockIdx.x & (NTIL - 1);
    const int bh  = blockIdx.x / NTIL;
    const int kb  = t * KBLK;

    const float* Kb = Kg + (size_t)bh * SEQ * DH;
    const float* Vb = Vg + (size_t)bh * SEQ * DH;
    short* kim = Kimg + ((size_t)bh * NTIL + t) * 4096;
    short* vim = Vimg + ((size_t)bh * NTIL + t) * 4096;

    // ---- K: row kr, d-group dc -> fragment-major image ----
    {
        const int kr = tid >> 2, dc = tid & 3;        // kr 0..63, dc 0..3
        const float* src = Kb + (size_t)(kb + kr) * DH + dc * 16;
        const float4 a0 = *reinterpret_cast<const float4*>(src);
        const float4 a1 = *reinterpret_cast<const float4*>(src + 4);
        const float4 a2 = *reinterpret_cast<const float4*>(src + 8);
        const float4 a3 = *reinterpret_cast<const float4*>(src + 12);
        V4U u0, u1;                                   // h=0: j 0..7; h=1: j 8..15
        u0.w[0] = cvtpk(a0.x, a0.y); u0.w[1] = cvtpk(a0.z, a0.w);
        u0.w[2] = cvtpk(a1.x, a1.y); u0.w[3] = cvtpk(a1.z, a1.w);
        u1.w[0] = cvtpk(a2.x, a2.y); u1.w[1] = cvtpk(a2.z, a2.w);
        u1.w[2] = cvtpk(a3.x, a3.y); u1.w[3] = cvtpk(a3.z, a3.w);
        const int sub = kr >> 5, row = kr & 31;
        *reinterpret_cast<bf16x8*>(&kim[dc * 1024 +   0 + sub * 256 + row * 8]) = u0.v;
        *reinterpret_cast<bf16x8*>(&kim[dc * 1024 + 512 + sub * 256 + row * 8]) = u1.v;
    }
    // ---- V: transpose via LDS, then fragment-major copy-out ----
    {
        const int vk = tid & 63, vd0 = (tid >> 6) * 16;
        const float* src = Vb + (size_t)(kb + vk) * DH + vd0;
        const float4 b0 = *reinterpret_cast<const float4*>(src);
        const float4 b1 = *reinterpret_cast<const float4*>(src + 4);
        const float4 b2 = *reinterpret_cast<const float4*>(src + 8);
        const float4 b3 = *reinterpret_cast<const float4*>(src + 12);
        const float vv[16] = {b0.x,b0.y,b0.z,b0.w, b1.x,b1.y,b1.z,b1.w,
                              b2.x,b2.y,b2.z,b2.w, b3.x,b3.y,b3.z,b3.w};
        #pragma unroll
        for (int i = 0; i < 16; ++i)
            Vt[swz(vd0 + i, vk)] = bfbits(vv[i]);
    }
    __syncthreads();
    #pragma unroll
    for (int c = 0; c < 2; ++c) {
        const int flat  = tid * 16 + c * 8;
        const int combo = flat >> 9;                  // kt*2 + h
        const int d     = (flat >> 3) & 63;
        const int col   = (combo >> 1) * 16 + (combo & 1) * 8;
        *reinterpret_cast<bf16x8*>(&vim[flat]) =
            *reinterpret_cast<const bf16x8*>(&Vt[swz(d, col)]);
    }
}

// ================= compute helpers =================
__device__ __forceinline__ void load_qfrags(const float* Qb, int q, int h, float SC,
                                            bf16x8 (&qb)[4]) {
    const float* qp = Qb + (size_t)q * DH + h * 8;
    #pragma unroll
    for (int dc = 0; dc < 4; ++dc) {
        const float4 a = *reinterpret_cast<const float4*>(qp + dc * 16);
        const float4 b = *reinterpret_cast<const float4*>(qp + dc * 16 + 4);
        V4U u;
        u.w[0] = cvtpk(a.x * SC, a.y * SC);
        u.w[1] = cvtpk(a.z * SC, a.w * SC);
        u.w[2] = cvtpk(b.x * SC, b.y * SC);
        u.w[3] = cvtpk(b.z * SC, b.w * SC);
        qb[dc] = u.v;
    }
}

// QK^T for one 32-row k-sub-block from the fragment-major K image
__device__ __forceinline__ f32x16 qk32g(const short* __restrict__ kt_, int sub, int ql, int h,
                                        const bf16x8 (&qb)[4]) {
    f32x16 s;
    #pragma unroll
    for (int i = 0; i < 16; ++i) s[i] = 0.f;
    bf16x8 kf[4];
    #pragma unroll
    for (int dc = 0; dc < 4; ++dc)
        kf[dc] = *reinterpret_cast<const bf16x8*>(&kt_[dc * 1024 + h * 512 + sub * 256 + ql * 8]);
    __builtin_amdgcn_s_setprio(1);
    #pragma unroll
    for (int dc = 0; dc < 4; ++dc)
        s = __builtin_amdgcn_mfma_f32_32x32x16_bf16(kf[dc], qb[dc], s, 0, 0, 0);
    __builtin_amdgcn_s_setprio(0);
    return s;
}

// mask + defer-max + exp(in-place) + pack into PV A-frags
__device__ __forceinline__ void sm_pack(f32x16& s0, f32x16& s1, bool v2,
                                        int kb, int qw, int q, int h,
                                        float& m, float& lsum,
                                        f32x16& o0, f32x16& o1, bf16x8 (&pa)[4]) {
    if (kb + 31 > qw) {
        #pragma unroll
        for (int r = 0; r < 16; ++r)
            if (kb + KPAT(r) + 4 * h > q) s0[r] = -1e30f;
    }
    if (v2 && (kb + 63 > qw)) {
        #pragma unroll
        for (int r = 0; r < 16; ++r)
            if (kb + 32 + KPAT(r) + 4 * h > q) s1[r] = -1e30f;
    }
    float mx = s0[0];
    #pragma unroll
    for (int r = 1; r < 16; ++r) mx = fmaxf(mx, s0[r]);
    if (v2) {
        #pragma unroll
        for (int r = 0; r < 16; ++r) mx = fmaxf(mx, s1[r]);
    }
    if (!__all(mx <= m + THR)) {
        mx = fmaxf(mx, __shfl_xor(mx, 32));
        const float mn  = fmaxf(m, mx);
        const float scl = __builtin_amdgcn_exp2f(m - mn);
        m = mn;
        lsum *= scl;
        #pragma unroll
        for (int r = 0; r < 16; ++r) {
            const float sr = __shfl(scl, KPAT(r) + 4 * h);
            o0[r] *= sr; o1[r] *= sr;
        }
    }
    #pragma unroll
    for (int r = 0; r < 16; ++r) { s0[r] = __builtin_amdgcn_exp2f(s0[r] - m); lsum += s0[r]; }
    #pragma unroll
    for (int oct = 0; oct < 2; ++oct) {
        const unsigned int A0 = cvtpk(s0[oct*8+0], s0[oct*8+1]);
        const unsigned int A1 = cvtpk(s0[oct*8+2], s0[oct*8+3]);
        const unsigned int B0 = cvtpk(s0[oct*8+4], s0[oct*8+5]);
        const unsigned int B1 = cvtpk(s0[oct*8+6], s0[oct*8+7]);
        const unsigned int t0 = h ? A0 : B0, t1 = h ? A1 : B1;
        const unsigned int r0 = (unsigned int)__shfl_xor((int)t0, 32);
        const unsigned int r1 = (unsigned int)__shfl_xor((int)t1, 32);
        V4U u;
        u.w[0] = h ? r0 : A0; u.w[1] = h ? r1 : A1;
        u.w[2] = h ? B0 : r0; u.w[3] = h ? B1 : r1;
        pa[oct] = u.v;
    }
    if (v2) {
        #pragma unroll
        for (int r = 0; r < 16; ++r) { s1[r] = __builtin_amdgcn_exp2f(s1[r] - m); lsum += s1[r]; }
        #pragma unroll
        for (int oct = 0; oct < 2; ++oct) {
            const unsigned int A0 = cvtpk(s1[oct*8+0], s1[oct*8+1]);
            const unsigned int A1 = cvtpk(s1[oct*8+2], s1[oct*8+3]);
            const unsigned int B0 = cvtpk(s1[oct*8+4], s1[oct*8+5]);
            const unsigned int B1 = cvtpk(s1[oct*8+6], s1[oct*8+7]);
            const unsigned int t0 = h ? A0 : B0, t1 = h ? A1 : B1;
            const unsigned int r0 = (unsigned int)__shfl_xor((int)t0, 32);
            const unsigned int r1 = (unsigned int)__shfl_xor((int)t1, 32);
            V4U u;
            u.w[0] = h ? r0 : A0; u.w[1] = h ? r1 : A1;
            u.w[2] = h ? B0 : r0; u.w[3] = h ? B1 : r1;
            pa[2 + oct] = u.v;
        }
    }
}

__device__ __forceinline__ void epilogue_store(float* Ob, int qw, int h, int ql,
                                               const f32x16& o0, const f32x16& o1,
                                               float lsum) {
    lsum += __shfl_xor(lsum, 32);
    const float inv = 1.0f / lsum;
    #pragma unroll
    for (int r = 0; r < 16; ++r) {
        const float ir  = __shfl(inv, KPAT(r) + 4 * h);
        const size_t row = (size_t)(qw + KPAT(r) + 4 * h);
        Ob[row * DH + ql]      = o0[r] * ir;
        Ob[row * DH + 32 + ql] = o1[r] * ir;
    }
}

// ================= main kernel: 1 wave / block + software tile prefetch =================
__global__ __launch_bounds__(64, 3) void attn_fwd(const float* __restrict__ Qg,
                                                  const short* __restrict__ Kimg,
                                                  const short* __restrict__ Vimg,
                                                  float* __restrict__ Og) {
    const int lane = threadIdx.x;
    const int h    = lane >> 5;
    const int ql   = lane & 31;

    // XCD-compact bh mapping + longest-first (R15 mapping, measured best)
    const int xcd  = blockIdx.x & 7;
    const int rest = blockIdx.x >> 3;
    const int bh   = xcd * 8 + (rest & 7);
    const int widx = rest >> 3;                    // 0..63
    const int qblk = (NQB - 1) - (widx >> 2);      // longest-first
    const int w    = widx & 3;

    const float* Qb   = Qg + (size_t)bh * SEQ * DH;
    const short* kimg = Kimg + (size_t)bh * NTIL * 4096;
    const short* vimg = Vimg + (size_t)bh * NTIL * 4096;
    float*       Ob   = Og + (size_t)bh * SEQ * DH;

    const float SC = 0.125f * 1.44269504f;         // 1/sqrt(64) * log2(e)

    const int qw   = qblk * QBLK + w * 32;         // wave's 32 q-rows
    const int q    = qw + ql;
    const int kend = qw + 32;                      // causal limit (exclusive)
    const int nt   = (kend + KBLK - 1) / KBLK;     // exactly the tiles this wave needs

    bf16x8 qb[4];
    load_qfrags(Qb, q, h, SC, qb);

    f32x16 o0, o1;
    #pragma unroll
    for (int i = 0; i < 16; ++i) { o0[i] = 0.f; o1[i] = 0.f; }
    float m = -1e30f, lsum = 0.f;

    for (int t = 0; t < nt; ++t) {
        const int kb = t * KBLK;
        const bool v2 = (kb + 32 < kend);
        const short* kt_ = kimg + (size_t)t * 4096;
        const short* vt_ = vimg + (size_t)t * 4096;

        // ---- software prefetch of tile t+1 (fire-and-forget; primes every
        //      128B line of the 8KB K and V images; waited only at iter end
        //      where the data has long arrived). Discriminator: helps iff
        //      the kernel is load-LATENCY-bound, not cache-BW-bound. ----
        const int tn = (t + 1 < nt) ? t + 1 : t;   // clamped, always in-bounds
        const char* kn = (const char*)(kimg + (size_t)tn * 4096);
        const char* vn = (const char*)(vimg + (size_t)tn * 4096);
        const unsigned int pf0 = *(const volatile unsigned int*)(kn + lane * 128);
        const unsigned int pf1 = *(const volatile unsigned int*)(vn + lane * 128);

        // QK^T from fragment-major K image
        f32x16 s0 = qk32g(kt_, 0, ql, h, qb);
        f32x16 s1;
        if (v2) s1 = qk32g(kt_, 1, ql, h, qb);

        // V fragments issued BEFORE softmax -> latency hides under it
        bf16x8 vf[8];
        #pragma unroll
        for (int kt = 0; kt < 4; ++kt) {
            vf[kt]     = *reinterpret_cast<const bf16x8*>(&vt_[kt * 1024 + h * 512 +       ql * 8]);
            vf[4 + kt] = *reinterpret_cast<const bf16x8*>(&vt_[kt * 1024 + h * 512 + 256 + ql * 8]);
        }

        bf16x8 pa[4];
        sm_pack(s0, s1, v2, kb, qw, q, h, m, lsum, o0, o1, pa);

        __builtin_amdgcn_s_setprio(1);
        #pragma unroll
        for (int kt = 0; kt < 2; ++kt) {
            o0 = __builtin_amdgcn_mfma_f32_32x32x16_bf16(pa[kt], vf[kt],     o0, 0, 0, 0);
            o1 = __builtin_amdgcn_mfma_f32_32x32x16_bf16(pa[kt], vf[4 + kt], o1, 0, 0, 0);
        }
        if (v2) {
            #pragma unroll
            for (int kt = 2; kt < 4; ++kt) {
                o0 = __builtin_amdgcn_mfma_f32_32x32x16_bf16(pa[kt], vf[kt],     o0, 0, 0, 0);
                o1 = __builtin_amdgcn_mfma_f32_32x32x16_bf16(pa[kt], vf[4 + kt], o1, 0, 0, 0);
            }
        }
        __builtin_amdgcn_s_setprio(0);

        // keep-alive: forces the prefetch loads to exist; wait lands here
        asm volatile("" :: "v"(pf0), "v"(pf1));
    }

    epilogue_store(Ob, qw, h, ql, o0, o1, lsum);
}

// ================= fallback (self-contained, used if ws too small) =================
__global__ __launch_bounds__(256) void attn_fwd_fb(const float* __restrict__ Qg,
                                                   const float* __restrict__ Kg,
                                                   const float* __restrict__ Vg,
                                                   float* __restrict__ Og) {
    __shared__ __align__(16) short Ks[64 * 64];
    __shared__ __align__(16) short Vt[64 * 64];

    const int tid  = threadIdx.x;
    const int w    = tid >> 6;
    const int lane = tid & 63;
    const int h    = lane >> 5;
    const int ql   = lane & 31;

    const int qblk = blockIdx.x & (NQB - 1);
    const int bh   = blockIdx.x / NQB;
    const int q0   = qblk * QBLK;
    const int qw   = q0 + w * 32;
    const int q    = qw + ql;

    const float* Qb = Qg + (size_t)bh * SEQ * DH;
    const float* Kb = Kg + (size_t)bh * SEQ * DH;
    const float* Vb = Vg + (size_t)bh * SEQ * DH;
    float*       Ob = Og + (size_t)bh * SEQ * DH;

    const float SC = 0.125f * 1.44269504f;

    const int skr  = tid >> 2;
    const int sd0  = (tid & 3) * 16;
    const int svk  = tid & 63;
    const int svd0 = (tid >> 6) * 16;

    bf16x8 qb[4];
    load_qfrags(Qb, q, h, SC, qb);

    f32x16 o0, o1;
    #pragma unroll
    for (int i = 0; i < 16; ++i) { o0[i] = 0.f; o1[i] = 0.f; }
    float m = -1e30f, lsum = 0.f;

    const int kend = qw + 32;
    const int nt   = (q0 + QBLK) / KBLK;

    for (int t = 0; t < nt; ++t) {
        const int kb = t * KBLK;
        __syncthreads();
        {
            const float* src = Kb + (size_t)(kb + skr) * DH + sd0;
            const float4 a0 = *reinterpret_cast<const float4*>(src);
            const float4 a1 = *reinterpret_cast<const float4*>(src + 4);
            const float4 a2 = *reinterpret_cast<const float4*>(src + 8);
            const float4 a3 = *reinterpret_cast<const float4*>(src + 12);
            V4U u0, u1;
            u0.w[0] = cvtpk(a0.x, a0.y); u0.w[1] = cvtpk(a0.z, a0.w);
            u0.w[2] = cvtpk(a1.x, a1.y); u0.w[3] = cvtpk(a1.z, a1.w);
            u1.w[0] = cvtpk(a2.x, a2.y); u1.w[1] = cvtpk(a2.z, a2.w);
            u1.w[2] = cvtpk(a3.x, a3.y); u1.w[3] = cvtpk(a3.z, a3.w);
            *reinterpret_cast<bf16x8*>(&Ks[swz(skr, sd0)])     = u0.v;
            *reinterpret_cast<bf16x8*>(&Ks[swz(skr, sd0 + 8)]) = u1.v;

            const float* vsrc = Vb + (size_t)(kb + svk) * DH + svd0;
            const float4 b0 = *reinterpret_cast<const float4*>(vsrc);
            const float4 b1 = *reinterpret_cast<const float4*>(vsrc + 4);
            const float4 b2 = *reinterpret_cast<const float4*>(vsrc + 8);
            const float4 b3 = *reinterpret_cast<const float4*>(vsrc + 12);
            const float vv[16] = {b0.x,b0.y,b0.z,b0.w, b1.x,b1.y,b1.z,b1.w,
                                  b2.x,b2.y,b2.z,b2.w, b3.x,b3.y,b3.z,b3.w};
            #pragma unroll
            for (int i = 0; i < 16; ++i)
                Vt[swz(svd0 + i, svk)] = bfbits(vv[i]);
        }
        __syncthreads();

        if (kb < kend) {
            const bool v2 = (kb + 32 < kend);
            f32x16 s0, s1;
            {
                bf16x8 kf[4];
                #pragma unroll
                for (int i = 0; i < 16; ++i) s0[i] = 0.f;
                #pragma unroll
                for (int dc = 0; dc < 4; ++dc)
                    kf[dc] = *reinterpret_cast<const bf16x8*>(&Ks[swz(ql, dc * 16 + h * 8)]);
                #pragma unroll
                for (int dc = 0; dc < 4; ++dc)
                    s0 = __builtin_amdgcn_mfma_f32_32x32x16_bf16(kf[dc], qb[dc], s0, 0, 0, 0);
                if (v2) {
                    #pragma unroll
                    for (int i = 0; i < 16; ++i) s1[i] = 0.f;
                    #pragma unroll
                    for (int dc = 0; dc < 4; ++dc)
                        kf[dc] = *reinterpret_cast<const bf16x8*>(&Ks[swz(32 + ql, dc * 16 + h * 8)]);
                    #pragma unroll
                    for (int dc = 0; dc < 4; ++dc)
                        s1 = __builtin_amdgcn_mfma_f32_32x32x16_bf16(kf[dc], qb[dc], s1, 0, 0, 0);
                }
            }
            bf16x8 pa[4];
            sm_pack(s0, s1, v2, kb, qw, q, h, m, lsum, o0, o1, pa);
            #pragma unroll
            for (int kt = 0; kt < 2; ++kt) {
                const bf16x8 vb0 = *reinterpret_cast<const bf16x8*>(&Vt[swz(ql,      kt * 16 + h * 8)]);
                const bf16x8 vb1 = *reinterpret_cast<const bf16x8*>(&Vt[swz(32 + ql, kt * 16 + h * 8)]);
                o0 = __builtin_amdgcn_mfma_f32_32x32x16_bf16(pa[kt], vb0, o0, 0, 0, 0);
                o1 = __builtin_amdgcn_mfma_f32_32x32x16_bf16(pa[kt], vb1, o1, 0, 0, 0);
            }
            if (v2) {
                #pragma unroll
                for (int kt = 2; kt < 4; ++kt) {
                    const bf16x8 vb0 = *reinterpret_cast<const bf16x8*>(&Vt[swz(ql,      kt * 16 + h * 8)]);
                    const bf16x8 vb1 = *reinterpret_cast<const bf16x8*>(&Vt[swz(32 + ql, kt * 16 + h * 8)]);
                    o0 = __builtin_amdgcn_mfma_f32_32x32x16_bf16(pa[kt], vb0, o0, 0, 0, 0);
                    o1 = __builtin_amdgcn_mfma_f32_32x32x16_bf16(pa[kt], vb1, o1, 0, 0, 0);
                }
            }
        }
    }

    epilogue_store(Ob, qw, h, ql, o0, o1, lsum);
}

extern "C" void kernel_launch(void* const* d_in, const int* in_sizes, int n_in,
                              void* d_out, int out_size, void* d_ws, size_t ws_size,
                              hipStream_t stream) {
    const float* Q = (const float*)d_in[0];
    const float* K = (const float*)d_in[1];
    const float* V = (const float*)d_in[2];
    // d_in[3] causal mask: synthesized in-kernel, not read.
    float* O = (float*)d_out;

    if (ws_size >= WS_NEEDED) {
        short* Kimg = (short*)d_ws;
        short* Vimg = Kimg + (size_t)64 * NTIL * 4096;
        prep_kv<<<dim3(64 * NTIL), 256, 0, stream>>>(K, V, Kimg, Vimg);
        attn_fwd<<<dim3(64 * 64), 64, 0, stream>>>(Q, Kimg, Vimg, O);
    } else {
        attn_fwd_fb<<<dim3(64 * NQB), 256, 0, stream>>>(Q, K, V, O);
    }
}

// Round 19
// 92.164 us; speedup vs baseline: 1.0705x; 1.0705x over previous
//
#include <hip/hip_runtime.h>

#define SEQ  2048
#define DH   64
#define QBLK 128         // q rows per q-block
#define KBLK 64          // k/v rows per tile
#define NQB  (SEQ/QBLK)  // 16
#define NTIL (SEQ/KBLK)  // 32 tiles per bh
#define THR  11.5f       // defer-max threshold (log2 domain)
#define KPAT(r) ((((r)&3)) + 8*((r)>>2))   // 32x32 C/D row pattern
#define WS_NEEDED ((size_t)2 * 64 * SEQ * DH * 2)   // K+V bf16 images = 33.5 MB

typedef short bf16x8 __attribute__((ext_vector_type(8)));   // 8 bf16 bits = 4 VGPRs
typedef float f32x16 __attribute__((ext_vector_type(16)));

union V4U { unsigned int w[4]; bf16x8 v; };

__device__ __forceinline__ short bfbits(float f) {
    unsigned int u = __float_as_uint(f);
    u += 0x7fff + ((u >> 16) & 1);
    return (short)(u >> 16);
}
__device__ __forceinline__ unsigned int cvtpk(float lo, float hi) {
    unsigned int r;
    asm("v_cvt_pk_bf16_f32 %0, %1, %2" : "=v"(r) : "v"(lo), "v"(hi));
    return r;
}
// swizzled short-index into a [rows][64] bf16 LDS tile (prep transpose only)
__device__ __forceinline__ int swz(int row, int col) {
    return row * 64 + (col ^ ((row & 7) << 3));
}

// ================= pre-pass: K/V -> bf16 FRAGMENT-MAJOR tile images =================
// K tile image layout (4096 shorts): idx = dc*1024 + h*512 + sub*256 + row32*8 + j
// V tile image layout: idx = kt*1024 + h*512 + d*8 + j  (d = 0..63 output dim)
__global__ __launch_bounds__(256) void prep_kv(const float* __restrict__ Kg,
                                               const float* __restrict__ Vg,
                                               short* __restrict__ Kimg,
                                               short* __restrict__ Vimg) {
    __shared__ __align__(16) short Vt[64 * 64];   // swizzled [d][k] transpose buffer
    const int tid = threadIdx.x;
    const int t   = blockIdx.x & (NTIL - 1);
    const int bh  = blockIdx.x / NTIL;
    const int kb  = t * KBLK;

    const float* Kb = Kg + (size_t)bh * SEQ * DH;
    const float* Vb = Vg + (size_t)bh * SEQ * DH;
    short* kim = Kimg + ((size_t)bh * NTIL + t) * 4096;
    short* vim = Vimg + ((size_t)bh * NTIL + t) * 4096;

    // ---- K: row kr, d-group dc -> fragment-major image ----
    {
        const int kr = tid >> 2, dc = tid & 3;        // kr 0..63, dc 0..3
        const float* src = Kb + (size_t)(kb + kr) * DH + dc * 16;
        const float4 a0 = *reinterpret_cast<const float4*>(src);
        const float4 a1 = *reinterpret_cast<const float4*>(src + 4);
        const float4 a2 = *reinterpret_cast<const float4*>(src + 8);
        const float4 a3 = *reinterpret_cast<const float4*>(src + 12);
        V4U u0, u1;                                   // h=0: j 0..7; h=1: j 8..15
        u0.w[0] = cvtpk(a0.x, a0.y); u0.w[1] = cvtpk(a0.z, a0.w);
        u0.w[2] = cvtpk(a1.x, a1.y); u0.w[3] = cvtpk(a1.z, a1.w);
        u1.w[0] = cvtpk(a2.x, a2.y); u1.w[1] = cvtpk(a2.z, a2.w);
        u1.w[2] = cvtpk(a3.x, a3.y); u1.w[3] = cvtpk(a3.z, a3.w);
        const int sub = kr >> 5, row = kr & 31;
        *reinterpret_cast<bf16x8*>(&kim[dc * 1024 +   0 + sub * 256 + row * 8]) = u0.v;
        *reinterpret_cast<bf16x8*>(&kim[dc * 1024 + 512 + sub * 256 + row * 8]) = u1.v;
    }
    // ---- V: transpose via LDS, then fragment-major copy-out ----
    {
        const int vk = tid & 63, vd0 = (tid >> 6) * 16;
        const float* src = Vb + (size_t)(kb + vk) * DH + vd0;
        const float4 b0 = *reinterpret_cast<const float4*>(src);
        const float4 b1 = *reinterpret_cast<const float4*>(src + 4);
        const float4 b2 = *reinterpret_cast<const float4*>(src + 8);
        const float4 b3 = *reinterpret_cast<const float4*>(src + 12);
        const float vv[16] = {b0.x,b0.y,b0.z,b0.w, b1.x,b1.y,b1.z,b1.w,
                              b2.x,b2.y,b2.z,b2.w, b3.x,b3.y,b3.z,b3.w};
        #pragma unroll
        for (int i = 0; i < 16; ++i)
            Vt[swz(vd0 + i, vk)] = bfbits(vv[i]);
    }
    __syncthreads();
    #pragma unroll
    for (int c = 0; c < 2; ++c) {
        const int flat  = tid * 16 + c * 8;
        const int combo = flat >> 9;                  // kt*2 + h
        const int d     = (flat >> 3) & 63;
        const int col   = (combo >> 1) * 16 + (combo & 1) * 8;
        *reinterpret_cast<bf16x8*>(&vim[flat]) =
            *reinterpret_cast<const bf16x8*>(&Vt[swz(d, col)]);
    }
}

// ================= compute helpers =================
__device__ __forceinline__ void load_qfrags(const float* Qb, int q, int h, float SC,
                                            bf16x8 (&qb)[4]) {
    const float* qp = Qb + (size_t)q * DH + h * 8;
    #pragma unroll
    for (int dc = 0; dc < 4; ++dc) {
        const float4 a = *reinterpret_cast<const float4*>(qp + dc * 16);
        const float4 b = *reinterpret_cast<const float4*>(qp + dc * 16 + 4);
        V4U u;
        u.w[0] = cvtpk(a.x * SC, a.y * SC);
        u.w[1] = cvtpk(a.z * SC, a.w * SC);
        u.w[2] = cvtpk(b.x * SC, b.y * SC);
        u.w[3] = cvtpk(b.z * SC, b.w * SC);
        qb[dc] = u.v;
    }
}

// QK^T for one 32-row k-sub-block from the fragment-major K image
__device__ __forceinline__ f32x16 qk32g(const short* __restrict__ kt_, int sub, int ql, int h,
                                        const bf16x8 (&qb)[4]) {
    f32x16 s;
    #pragma unroll
    for (int i = 0; i < 16; ++i) s[i] = 0.f;
    bf16x8 kf[4];
    #pragma unroll
    for (int dc = 0; dc < 4; ++dc)
        kf[dc] = *reinterpret_cast<const bf16x8*>(&kt_[dc * 1024 + h * 512 + sub * 256 + ql * 8]);
    __builtin_amdgcn_s_setprio(1);
    #pragma unroll
    for (int dc = 0; dc < 4; ++dc)
        s = __builtin_amdgcn_mfma_f32_32x32x16_bf16(kf[dc], qb[dc], s, 0, 0, 0);
    __builtin_amdgcn_s_setprio(0);
    return s;
}

// mask + defer-max + exp(in-place) + pack into PV A-frags
__device__ __forceinline__ void sm_pack(f32x16& s0, f32x16& s1, bool v2,
                                        int kb, int qw, int q, int h,
                                        float& m, float& lsum,
                                        f32x16& o0, f32x16& o1, bf16x8 (&pa)[4]) {
    if (kb + 31 > qw) {
        #pragma unroll
        for (int r = 0; r < 16; ++r)
            if (kb + KPAT(r) + 4 * h > q) s0[r] = -1e30f;
    }
    if (v2 && (kb + 63 > qw)) {
        #pragma unroll
        for (int r = 0; r < 16; ++r)
            if (kb + 32 + KPAT(r) + 4 * h > q) s1[r] = -1e30f;
    }
    float mx = s0[0];
    #pragma unroll
    for (int r = 1; r < 16; ++r) mx = fmaxf(mx, s0[r]);
    if (v2) {
        #pragma unroll
        for (int r = 0; r < 16; ++r) mx = fmaxf(mx, s1[r]);
    }
    if (!__all(mx <= m + THR)) {
        mx = fmaxf(mx, __shfl_xor(mx, 32));
        const float mn  = fmaxf(m, mx);
        const float scl = __builtin_amdgcn_exp2f(m - mn);
        m = mn;
        lsum *= scl;
        #pragma unroll
        for (int r = 0; r < 16; ++r) {
            const float sr = __shfl(scl, KPAT(r) + 4 * h);
            o0[r] *= sr; o1[r] *= sr;
        }
    }
    #pragma unroll
    for (int r = 0; r < 16; ++r) { s0[r] = __builtin_amdgcn_exp2f(s0[r] - m); lsum += s0[r]; }
    #pragma unroll
    for (int oct = 0; oct < 2; ++oct) {
        const unsigned int A0 = cvtpk(s0[oct*8+0], s0[oct*8+1]);
        const unsigned int A1 = cvtpk(s0[oct*8+2], s0[oct*8+3]);
        const unsigned int B0 = cvtpk(s0[oct*8+4], s0[oct*8+5]);
        const unsigned int B1 = cvtpk(s0[oct*8+6], s0[oct*8+7]);
        const unsigned int t0 = h ? A0 : B0, t1 = h ? A1 : B1;
        const unsigned int r0 = (unsigned int)__shfl_xor((int)t0, 32);
        const unsigned int r1 = (unsigned int)__shfl_xor((int)t1, 32);
        V4U u;
        u.w[0] = h ? r0 : A0; u.w[1] = h ? r1 : A1;
        u.w[2] = h ? B0 : r0; u.w[3] = h ? B1 : r1;
        pa[oct] = u.v;
    }
    if (v2) {
        #pragma unroll
        for (int r = 0; r < 16; ++r) { s1[r] = __builtin_amdgcn_exp2f(s1[r] - m); lsum += s1[r]; }
        #pragma unroll
        for (int oct = 0; oct < 2; ++oct) {
            const unsigned int A0 = cvtpk(s1[oct*8+0], s1[oct*8+1]);
            const unsigned int A1 = cvtpk(s1[oct*8+2], s1[oct*8+3]);
            const unsigned int B0 = cvtpk(s1[oct*8+4], s1[oct*8+5]);
            const unsigned int B1 = cvtpk(s1[oct*8+6], s1[oct*8+7]);
            const unsigned int t0 = h ? A0 : B0, t1 = h ? A1 : B1;
            const unsigned int r0 = (unsigned int)__shfl_xor((int)t0, 32);
            const unsigned int r1 = (unsigned int)__shfl_xor((int)t1, 32);
            V4U u;
            u.w[0] = h ? r0 : A0; u.w[1] = h ? r1 : A1;
            u.w[2] = h ? B0 : r0; u.w[3] = h ? B1 : r1;
            pa[2 + oct] = u.v;
        }
    }
}

// O is written once and never re-read -> nontemporal stores keep it from
// evicting the K/V images out of L2.
__device__ __forceinline__ void epilogue_store(float* Ob, int qw, int h, int ql,
                                               const f32x16& o0, const f32x16& o1,
                                               float lsum) {
    lsum += __shfl_xor(lsum, 32);
    const float inv = 1.0f / lsum;
    #pragma unroll
    for (int r = 0; r < 16; ++r) {
        const float ir  = __shfl(inv, KPAT(r) + 4 * h);
        const size_t row = (size_t)(qw + KPAT(r) + 4 * h);
        __builtin_nontemporal_store(o0[r] * ir, &Ob[row * DH + ql]);
        __builtin_nontemporal_store(o1[r] * ir, &Ob[row * DH + 32 + ql]);
    }
}

// ================= main kernel: 1 wave / block; bh advances SLOWEST in XCD =================
__global__ __launch_bounds__(64, 3) void attn_fwd(const float* __restrict__ Qg,
                                                  const short* __restrict__ Kimg,
                                                  const short* __restrict__ Vimg,
                                                  float* __restrict__ Og) {
    const int lane = threadIdx.x;
    const int h    = lane >> 5;
    const int ql   = lane & 31;

    // Concurrent-working-set fix: dispatcher assigns XCD ~ bid%8; within an
    // XCD ~96 blocks are co-resident. R15 cycled bh FASTEST (rest&7), so those
    // 96 blocks spanned all 8 bh = 4.2MB of K/V images > 4MB L2 -> contended-L3
    // misses. Here widx cycles fastest and bh advances SLOWEST: the co-resident
    // blocks span ~1.5 bh (~0.8MB) -> fragment loads are L2 hits.
    const int xcd  = blockIdx.x & 7;
    const int rest = blockIdx.x >> 3;              // 0..511
    const int bh   = xcd * 8 + (rest >> 6);        // slowest
    const int widx = rest & 63;                    // fastest
    const int qblk = (NQB - 1) - (widx >> 2);      // longest-first within bh
    const int w    = widx & 3;

    const float* Qb   = Qg + (size_t)bh * SEQ * DH;
    const short* kimg = Kimg + (size_t)bh * NTIL * 4096;
    const short* vimg = Vimg + (size_t)bh * NTIL * 4096;
    float*       Ob   = Og + (size_t)bh * SEQ * DH;

    const float SC = 0.125f * 1.44269504f;         // 1/sqrt(64) * log2(e)

    const int qw   = qblk * QBLK + w * 32;         // wave's 32 q-rows
    const int q    = qw + ql;
    const int kend = qw + 32;                      // causal limit (exclusive)
    const int nt   = (kend + KBLK - 1) / KBLK;     // exactly the tiles this wave needs

    bf16x8 qb[4];
    load_qfrags(Qb, q, h, SC, qb);

    f32x16 o0, o1;
    #pragma unroll
    for (int i = 0; i < 16; ++i) { o0[i] = 0.f; o1[i] = 0.f; }
    float m = -1e30f, lsum = 0.f;

    for (int t = 0; t < nt; ++t) {
        const int kb = t * KBLK;
        const bool v2 = (kb + 32 < kend);
        const short* kt_ = kimg + (size_t)t * 4096;
        const short* vt_ = vimg + (size_t)t * 4096;

        // QK^T from fragment-major K image (coalesced loads)
        f32x16 s0 = qk32g(kt_, 0, ql, h, qb);
        f32x16 s1;
        if (v2) s1 = qk32g(kt_, 1, ql, h, qb);

        // V fragments issued BEFORE softmax -> latency hides under it
        bf16x8 vf[8];
        #pragma unroll
        for (int kt = 0; kt < 4; ++kt) {
            vf[kt]     = *reinterpret_cast<const bf16x8*>(&vt_[kt * 1024 + h * 512 +       ql * 8]);
            vf[4 + kt] = *reinterpret_cast<const bf16x8*>(&vt_[kt * 1024 + h * 512 + 256 + ql * 8]);
        }

        bf16x8 pa[4];
        sm_pack(s0, s1, v2, kb, qw, q, h, m, lsum, o0, o1, pa);

        __builtin_amdgcn_s_setprio(1);
        #pragma unroll
        for (int kt = 0; kt < 2; ++kt) {
            o0 = __builtin_amdgcn_mfma_f32_32x32x16_bf16(pa[kt], vf[kt],     o0, 0, 0, 0);
            o1 = __builtin_amdgcn_mfma_f32_32x32x16_bf16(pa[kt], vf[4 + kt], o1, 0, 0, 0);
        }
        if (v2) {
            #pragma unroll
            for (int kt = 2; kt < 4; ++kt) {
                o0 = __builtin_amdgcn_mfma_f32_32x32x16_bf16(pa[kt], vf[kt],     o0, 0, 0, 0);
                o1 = __builtin_amdgcn_mfma_f32_32x32x16_bf16(pa[kt], vf[4 + kt], o1, 0, 0, 0);
            }
        }
        __builtin_amdgcn_s_setprio(0);
    }

    epilogue_store(Ob, qw, h, ql, o0, o1, lsum);
}

// ================= fallback (self-contained, used if ws too small) =================
__global__ __launch_bounds__(256) void attn_fwd_fb(const float* __restrict__ Qg,
                                                   const float* __restrict__ Kg,
                                                   const float* __restrict__ Vg,
                                                   float* __restrict__ Og) {
    __shared__ __align__(16) short Ks[64 * 64];
    __shared__ __align__(16) short Vt[64 * 64];

    const int tid  = threadIdx.x;
    const int w    = tid >> 6;
    const int lane = tid & 63;
    const int h    = lane >> 5;
    const int ql   = lane & 31;

    const int qblk = blockIdx.x & (NQB - 1);
    const int bh   = blockIdx.x / NQB;
    const int q0   = qblk * QBLK;
    const int qw   = q0 + w * 32;
    const int q    = qw + ql;

    const float* Qb = Qg + (size_t)bh * SEQ * DH;
    const float* Kb = Kg + (size_t)bh * SEQ * DH;
    const float* Vb = Vg + (size_t)bh * SEQ * DH;
    float*       Ob = Og + (size_t)bh * SEQ * DH;

    const float SC = 0.125f * 1.44269504f;

    const int skr  = tid >> 2;
    const int sd0  = (tid & 3) * 16;
    const int svk  = tid & 63;
    const int svd0 = (tid >> 6) * 16;

    bf16x8 qb[4];
    load_qfrags(Qb, q, h, SC, qb);

    f32x16 o0, o1;
    #pragma unroll
    for (int i = 0; i < 16; ++i) { o0[i] = 0.f; o1[i] = 0.f; }
    float m = -1e30f, lsum = 0.f;

    const int kend = qw + 32;
    const int nt   = (q0 + QBLK) / KBLK;

    for (int t = 0; t < nt; ++t) {
        const int kb = t * KBLK;
        __syncthreads();
        {
            const float* src = Kb + (size_t)(kb + skr) * DH + sd0;
            const float4 a0 = *reinterpret_cast<const float4*>(src);
            const float4 a1 = *reinterpret_cast<const float4*>(src + 4);
            const float4 a2 = *reinterpret_cast<const float4*>(src + 8);
            const float4 a3 = *reinterpret_cast<const float4*>(src + 12);
            V4U u0, u1;
            u0.w[0] = cvtpk(a0.x, a0.y); u0.w[1] = cvtpk(a0.z, a0.w);
            u0.w[2] = cvtpk(a1.x, a1.y); u0.w[3] = cvtpk(a1.z, a1.w);
            u1.w[0] = cvtpk(a2.x, a2.y); u1.w[1] = cvtpk(a2.z, a2.w);
            u1.w[2] = cvtpk(a3.x, a3.y); u1.w[3] = cvtpk(a3.z, a3.w);
            *reinterpret_cast<bf16x8*>(&Ks[swz(skr, sd0)])     = u0.v;
            *reinterpret_cast<bf16x8*>(&Ks[swz(skr, sd0 + 8)]) = u1.v;

            const float* vsrc = Vb + (size_t)(kb + svk) * DH + svd0;
            const float4 b0 = *reinterpret_cast<const float4*>(vsrc);
            const float4 b1 = *reinterpret_cast<const float4*>(vsrc + 4);
            const float4 b2 = *reinterpret_cast<const float4*>(vsrc + 8);
            const float4 b3 = *reinterpret_cast<const float4*>(vsrc + 12);
            const float vv[16] = {b0.x,b0.y,b0.z,b0.w, b1.x,b1.y,b1.z,b1.w,
                                  b2.x,b2.y,b2.z,b2.w, b3.x,b3.y,b3.z,b3.w};
            #pragma unroll
            for (int i = 0; i < 16; ++i)
                Vt[swz(svd0 + i, svk)] = bfbits(vv[i]);
        }
        __syncthreads();

        if (kb < kend) {
            const bool v2 = (kb + 32 < kend);
            f32x16 s0, s1;
            {
                bf16x8 kf[4];
                #pragma unroll
                for (int i = 0; i < 16; ++i) s0[i] = 0.f;
                #pragma unroll
                for (int dc = 0; dc < 4; ++dc)
                    kf[dc] = *reinterpret_cast<const bf16x8*>(&Ks[swz(ql, dc * 16 + h * 8)]);
                #pragma unroll
                for (int dc = 0; dc < 4; ++dc)
                    s0 = __builtin_amdgcn_mfma_f32_32x32x16_bf16(kf[dc], qb[dc], s0, 0, 0, 0);
                if (v2) {
                    #pragma unroll
                    for (int i = 0; i < 16; ++i) s1[i] = 0.f;
                    #pragma unroll
                    for (int dc = 0; dc < 4; ++dc)
                        kf[dc] = *reinterpret_cast<const bf16x8*>(&Ks[swz(32 + ql, dc * 16 + h * 8)]);
                    #pragma unroll
                    for (int dc = 0; dc < 4; ++dc)
                        s1 = __builtin_amdgcn_mfma_f32_32x32x16_bf16(kf[dc], qb[dc], s1, 0, 0, 0);
                }
            }
            bf16x8 pa[4];
            sm_pack(s0, s1, v2, kb, qw, q, h, m, lsum, o0, o1, pa);
            #pragma unroll
            for (int kt = 0; kt < 2; ++kt) {
                const bf16x8 vb0 = *reinterpret_cast<const bf16x8*>(&Vt[swz(ql,      kt * 16 + h * 8)]);
                const bf16x8 vb1 = *reinterpret_cast<const bf16x8*>(&Vt[swz(32 + ql, kt * 16 + h * 8)]);
                o0 = __builtin_amdgcn_mfma_f32_32x32x16_bf16(pa[kt], vb0, o0, 0, 0, 0);
                o1 = __builtin_amdgcn_mfma_f32_32x32x16_bf16(pa[kt], vb1, o1, 0, 0, 0);
            }
            if (v2) {
                #pragma unroll
                for (int kt = 2; kt < 4; ++kt) {
                    const bf16x8 vb0 = *reinterpret_cast<const bf16x8*>(&Vt[swz(ql,      kt * 16 + h * 8)]);
                    const bf16x8 vb1 = *reinterpret_cast<const bf16x8*>(&Vt[swz(32 + ql, kt * 16 + h * 8)]);
                    o0 = __builtin_amdgcn_mfma_f32_32x32x16_bf16(pa[kt], vb0, o0, 0, 0, 0);
                    o1 = __builtin_amdgcn_mfma_f32_32x32x16_bf16(pa[kt], vb1, o1, 0, 0, 0);
                }
            }
        }
    }

    epilogue_store(Ob, qw, h, ql, o0, o1, lsum);
}

extern "C" void kernel_launch(void* const* d_in, const int* in_sizes, int n_in,
                              void* d_out, int out_size, void* d_ws, size_t ws_size,
                              hipStream_t stream) {
    const float* Q = (const float*)d_in[0];
    const float* K = (const float*)d_in[1];
    const float* V = (const float*)d_in[2];
    // d_in[3] causal mask: synthesized in-kernel, not read.
    float* O = (float*)d_out;

    if (ws_size >= WS_NEEDED) {
        short* Kimg = (short*)d_ws;
        short* Vimg = Kimg + (size_t)64 * NTIL * 4096;
        prep_kv<<<dim3(64 * NTIL), 256, 0, stream>>>(K, V, Kimg, Vimg);
        attn_fwd<<<dim3(64 * 64), 64, 0, stream>>>(Q, Kimg, Vimg, O);
    } else {
        attn_fwd_fb<<<dim3(64 * NQB), 256, 0, stream>>>(Q, K, V, O);
    }
}

// Round 20
// 79.203 us; speedup vs baseline: 1.2457x; 1.1636x over previous
//
#include <hip/hip_runtime.h>

#define SEQ  2048
#define DH   64
#define QBLK 128         // q rows per q-block
#define KBLK 64          // k/v rows per tile
#define NQB  (SEQ/QBLK)  // 16
#define NTIL (SEQ/KBLK)  // 32 tiles per bh
#define THR  11.5f       // defer-max threshold (log2 domain)
#define KPAT(r) ((((r)&3)) + 8*((r)>>2))   // 32x32 C/D row pattern
#define WS_NEEDED ((size_t)2 * 64 * SEQ * DH * 2)   // K+V bf16 images = 33.5 MB

typedef short bf16x8 __attribute__((ext_vector_type(8)));   // 8 bf16 bits = 4 VGPRs
typedef float f32x16 __attribute__((ext_vector_type(16)));

union V4U { unsigned int w[4]; bf16x8 v; };

__device__ __forceinline__ short bfbits(float f) {
    unsigned int u = __float_as_uint(f);
    u += 0x7fff + ((u >> 16) & 1);
    return (short)(u >> 16);
}
__device__ __forceinline__ unsigned int cvtpk(float lo, float hi) {
    unsigned int r;
    asm("v_cvt_pk_bf16_f32 %0, %1, %2" : "=v"(r) : "v"(lo), "v"(hi));
    return r;
}
// swizzled short-index into a [rows][64] bf16 LDS tile (prep transpose only)
__device__ __forceinline__ int swz(int row, int col) {
    return row * 64 + (col ^ ((row & 7) << 3));
}

// ================= pre-pass: K/V -> bf16 FRAGMENT-MAJOR tile images =================
// K tile image layout (4096 shorts): idx = dc*1024 + h*512 + sub*256 + row32*8 + j
// V tile image layout: idx = kt*1024 + h*512 + d*8 + j  (d = 0..63 output dim)
__global__ __launch_bounds__(256) void prep_kv(const float* __restrict__ Kg,
                                               const float* __restrict__ Vg,
                                               short* __restrict__ Kimg,
                                               short* __restrict__ Vimg) {
    __shared__ __align__(16) short Vt[64 * 64];   // swizzled [d][k] transpose buffer
    const int tid = threadIdx.x;
    const int t   = blockIdx.x & (NTIL - 1);
    const int bh  = blockIdx.x / NTIL;
    const int kb  = t * KBLK;

    const float* Kb = Kg + (size_t)bh * SEQ * DH;
    const float* Vb = Vg + (size_t)bh * SEQ * DH;
    short* kim = Kimg + ((size_t)bh * NTIL + t) * 4096;
    short* vim = Vimg + ((size_t)bh * NTIL + t) * 4096;

    // ---- K: row kr, d-group dc -> fragment-major image ----
    {
        const int kr = tid >> 2, dc = tid & 3;        // kr 0..63, dc 0..3
        const float* src = Kb + (size_t)(kb + kr) * DH + dc * 16;
        const float4 a0 = *reinterpret_cast<const float4*>(src);
        const float4 a1 = *reinterpret_cast<const float4*>(src + 4);
        const float4 a2 = *reinterpret_cast<const float4*>(src + 8);
        const float4 a3 = *reinterpret_cast<const float4*>(src + 12);
        V4U u0, u1;                                   // h=0: j 0..7; h=1: j 8..15
        u0.w[0] = cvtpk(a0.x, a0.y); u0.w[1] = cvtpk(a0.z, a0.w);
        u0.w[2] = cvtpk(a1.x, a1.y); u0.w[3] = cvtpk(a1.z, a1.w);
        u1.w[0] = cvtpk(a2.x, a2.y); u1.w[1] = cvtpk(a2.z, a2.w);
        u1.w[2] = cvtpk(a3.x, a3.y); u1.w[3] = cvtpk(a3.z, a3.w);
        const int sub = kr >> 5, row = kr & 31;
        *reinterpret_cast<bf16x8*>(&kim[dc * 1024 +   0 + sub * 256 + row * 8]) = u0.v;
        *reinterpret_cast<bf16x8*>(&kim[dc * 1024 + 512 + sub * 256 + row * 8]) = u1.v;
    }
    // ---- V: transpose via LDS, then fragment-major copy-out ----
    {
        const int vk = tid & 63, vd0 = (tid >> 6) * 16;
        const float* src = Vb + (size_t)(kb + vk) * DH + vd0;
        const float4 b0 = *reinterpret_cast<const float4*>(src);
        const float4 b1 = *reinterpret_cast<const float4*>(src + 4);
        const float4 b2 = *reinterpret_cast<const float4*>(src + 8);
        const float4 b3 = *reinterpret_cast<const float4*>(src + 12);
        const float vv[16] = {b0.x,b0.y,b0.z,b0.w, b1.x,b1.y,b1.z,b1.w,
                              b2.x,b2.y,b2.z,b2.w, b3.x,b3.y,b3.z,b3.w};
        #pragma unroll
        for (int i = 0; i < 16; ++i)
            Vt[swz(vd0 + i, vk)] = bfbits(vv[i]);
    }
    __syncthreads();
    #pragma unroll
    for (int c = 0; c < 2; ++c) {
        const int flat  = tid * 16 + c * 8;
        const int combo = flat >> 9;                  // kt*2 + h
        const int d     = (flat >> 3) & 63;
        const int col   = (combo >> 1) * 16 + (combo & 1) * 8;
        *reinterpret_cast<bf16x8*>(&vim[flat]) =
            *reinterpret_cast<const bf16x8*>(&Vt[swz(d, col)]);
    }
}

// ================= compute helpers =================
__device__ __forceinline__ void load_qfrags(const float* Qb, int q, int h, float SC,
                                            bf16x8 (&qb)[4]) {
    const float* qp = Qb + (size_t)q * DH + h * 8;
    #pragma unroll
    for (int dc = 0; dc < 4; ++dc) {
        const float4 a = *reinterpret_cast<const float4*>(qp + dc * 16);
        const float4 b = *reinterpret_cast<const float4*>(qp + dc * 16 + 4);
        V4U u;
        u.w[0] = cvtpk(a.x * SC, a.y * SC);
        u.w[1] = cvtpk(a.z * SC, a.w * SC);
        u.w[2] = cvtpk(b.x * SC, b.y * SC);
        u.w[3] = cvtpk(b.z * SC, b.w * SC);
        qb[dc] = u.v;
    }
}

// QK^T for one 32-row k-sub-block from the fragment-major K image
__device__ __forceinline__ f32x16 qk32g(const short* __restrict__ kt_, int sub, int ql, int h,
                                        const bf16x8 (&qb)[4]) {
    f32x16 s;
    #pragma unroll
    for (int i = 0; i < 16; ++i) s[i] = 0.f;
    bf16x8 kf[4];
    #pragma unroll
    for (int dc = 0; dc < 4; ++dc)
        kf[dc] = *reinterpret_cast<const bf16x8*>(&kt_[dc * 1024 + h * 512 + sub * 256 + ql * 8]);
    __builtin_amdgcn_s_setprio(1);
    #pragma unroll
    for (int dc = 0; dc < 4; ++dc)
        s = __builtin_amdgcn_mfma_f32_32x32x16_bf16(kf[dc], qb[dc], s, 0, 0, 0);
    __builtin_amdgcn_s_setprio(0);
    return s;
}

// mask + defer-max + exp(in-place) + pack into PV A-frags
__device__ __forceinline__ void sm_pack(f32x16& s0, f32x16& s1, bool v2,
                                        int kb, int qw, int q, int h,
                                        float& m, float& lsum,
                                        f32x16& o0, f32x16& o1, bf16x8 (&pa)[4]) {
    if (kb + 31 > qw) {
        #pragma unroll
        for (int r = 0; r < 16; ++r)
            if (kb + KPAT(r) + 4 * h > q) s0[r] = -1e30f;
    }
    if (v2 && (kb + 63 > qw)) {
        #pragma unroll
        for (int r = 0; r < 16; ++r)
            if (kb + 32 + KPAT(r) + 4 * h > q) s1[r] = -1e30f;
    }
    float mx = s0[0];
    #pragma unroll
    for (int r = 1; r < 16; ++r) mx = fmaxf(mx, s0[r]);
    if (v2) {
        #pragma unroll
        for (int r = 0; r < 16; ++r) mx = fmaxf(mx, s1[r]);
    }
    if (!__all(mx <= m + THR)) {
        mx = fmaxf(mx, __shfl_xor(mx, 32));
        const float mn  = fmaxf(m, mx);
        const float scl = __builtin_amdgcn_exp2f(m - mn);
        m = mn;
        lsum *= scl;
        #pragma unroll
        for (int r = 0; r < 16; ++r) {
            const float sr = __shfl(scl, KPAT(r) + 4 * h);
            o0[r] *= sr; o1[r] *= sr;
        }
    }
    #pragma unroll
    for (int r = 0; r < 16; ++r) { s0[r] = __builtin_amdgcn_exp2f(s0[r] - m); lsum += s0[r]; }
    #pragma unroll
    for (int oct = 0; oct < 2; ++oct) {
        const unsigned int A0 = cvtpk(s0[oct*8+0], s0[oct*8+1]);
        const unsigned int A1 = cvtpk(s0[oct*8+2], s0[oct*8+3]);
        const unsigned int B0 = cvtpk(s0[oct*8+4], s0[oct*8+5]);
        const unsigned int B1 = cvtpk(s0[oct*8+6], s0[oct*8+7]);
        const unsigned int t0 = h ? A0 : B0, t1 = h ? A1 : B1;
        const unsigned int r0 = (unsigned int)__shfl_xor((int)t0, 32);
        const unsigned int r1 = (unsigned int)__shfl_xor((int)t1, 32);
        V4U u;
        u.w[0] = h ? r0 : A0; u.w[1] = h ? r1 : A1;
        u.w[2] = h ? B0 : r0; u.w[3] = h ? B1 : r1;
        pa[oct] = u.v;
    }
    if (v2) {
        #pragma unroll
        for (int r = 0; r < 16; ++r) { s1[r] = __builtin_amdgcn_exp2f(s1[r] - m); lsum += s1[r]; }
        #pragma unroll
        for (int oct = 0; oct < 2; ++oct) {
            const unsigned int A0 = cvtpk(s1[oct*8+0], s1[oct*8+1]);
            const unsigned int A1 = cvtpk(s1[oct*8+2], s1[oct*8+3]);
            const unsigned int B0 = cvtpk(s1[oct*8+4], s1[oct*8+5]);
            const unsigned int B1 = cvtpk(s1[oct*8+6], s1[oct*8+7]);
            const unsigned int t0 = h ? A0 : B0, t1 = h ? A1 : B1;
            const unsigned int r0 = (unsigned int)__shfl_xor((int)t0, 32);
            const unsigned int r1 = (unsigned int)__shfl_xor((int)t1, 32);
            V4U u;
            u.w[0] = h ? r0 : A0; u.w[1] = h ? r1 : A1;
            u.w[2] = h ? B0 : r0; u.w[3] = h ? B1 : r1;
            pa[2 + oct] = u.v;
        }
    }
}

__device__ __forceinline__ void epilogue_store(float* Ob, int qw, int h, int ql,
                                               const f32x16& o0, const f32x16& o1,
                                               float lsum) {
    lsum += __shfl_xor(lsum, 32);
    const float inv = 1.0f / lsum;
    #pragma unroll
    for (int r = 0; r < 16; ++r) {
        const float ir  = __shfl(inv, KPAT(r) + 4 * h);
        const size_t row = (size_t)(qw + KPAT(r) + 4 * h);
        Ob[row * DH + ql]      = o0[r] * ir;
        Ob[row * DH + 32 + ql] = o1[r] * ir;
    }
}

// ================= main kernel: 1 wave / block, no LDS, XCD-local bh mapping =================
__global__ __launch_bounds__(64, 3) void attn_fwd(const float* __restrict__ Qg,
                                                  const short* __restrict__ Kimg,
                                                  const short* __restrict__ Vimg,
                                                  float* __restrict__ Og) {
    const int lane = threadIdx.x;
    const int h    = lane >> 5;
    const int ql   = lane & 31;

    // R15 mapping (best measured): XCD-compact bh groups + longest-first waves.
    const int xcd  = blockIdx.x & 7;
    const int rest = blockIdx.x >> 3;
    const int bh   = xcd * 8 + (rest & 7);
    const int widx = rest >> 3;                    // 0..63
    const int qblk = (NQB - 1) - (widx >> 2);      // longest-first
    const int w    = widx & 3;

    const float* Qb   = Qg + (size_t)bh * SEQ * DH;
    const short* kimg = Kimg + (size_t)bh * NTIL * 4096;
    const short* vimg = Vimg + (size_t)bh * NTIL * 4096;
    float*       Ob   = Og + (size_t)bh * SEQ * DH;

    const float SC = 0.125f * 1.44269504f;         // 1/sqrt(64) * log2(e)

    const int qw   = qblk * QBLK + w * 32;         // wave's 32 q-rows
    const int q    = qw + ql;
    const int kend = qw + 32;                      // causal limit (exclusive)
    const int nt   = (kend + KBLK - 1) / KBLK;     // exactly the tiles this wave needs

    bf16x8 qb[4];
    load_qfrags(Qb, q, h, SC, qb);

    f32x16 o0, o1;
    #pragma unroll
    for (int i = 0; i < 16; ++i) { o0[i] = 0.f; o1[i] = 0.f; }
    float m = -1e30f, lsum = 0.f;

    for (int t = 0; t < nt; ++t) {
        const int kb = t * KBLK;
        const bool v2 = (kb + 32 < kend);
        const short* kt_ = kimg + (size_t)t * 4096;
        const short* vt_ = vimg + (size_t)t * 4096;

        // QK^T from fragment-major K image (coalesced global loads)
        f32x16 s0 = qk32g(kt_, 0, ql, h, qb);
        f32x16 s1;
        if (v2) s1 = qk32g(kt_, 1, ql, h, qb);

        // V fragments issued BEFORE softmax -> latency hides under it
        bf16x8 vf[8];
        #pragma unroll
        for (int kt = 0; kt < 4; ++kt) {
            vf[kt]     = *reinterpret_cast<const bf16x8*>(&vt_[kt * 1024 + h * 512 +       ql * 8]);
            vf[4 + kt] = *reinterpret_cast<const bf16x8*>(&vt_[kt * 1024 + h * 512 + 256 + ql * 8]);
        }

        bf16x8 pa[4];
        sm_pack(s0, s1, v2, kb, qw, q, h, m, lsum, o0, o1, pa);

        __builtin_amdgcn_s_setprio(1);
        #pragma unroll
        for (int kt = 0; kt < 2; ++kt) {
            o0 = __builtin_amdgcn_mfma_f32_32x32x16_bf16(pa[kt], vf[kt],     o0, 0, 0, 0);
            o1 = __builtin_amdgcn_mfma_f32_32x32x16_bf16(pa[kt], vf[4 + kt], o1, 0, 0, 0);
        }
        if (v2) {
            #pragma unroll
            for (int kt = 2; kt < 4; ++kt) {
                o0 = __builtin_amdgcn_mfma_f32_32x32x16_bf16(pa[kt], vf[kt],     o0, 0, 0, 0);
                o1 = __builtin_amdgcn_mfma_f32_32x32x16_bf16(pa[kt], vf[4 + kt], o1, 0, 0, 0);
            }
        }
        __builtin_amdgcn_s_setprio(0);
    }

    epilogue_store(Ob, qw, h, ql, o0, o1, lsum);
}

// ================= fallback (self-contained, used if ws too small) =================
__global__ __launch_bounds__(256) void attn_fwd_fb(const float* __restrict__ Qg,
                                                   const float* __restrict__ Kg,
                                                   const float* __restrict__ Vg,
                                                   float* __restrict__ Og) {
    __shared__ __align__(16) short Ks[64 * 64];
    __shared__ __align__(16) short Vt[64 * 64];

    const int tid  = threadIdx.x;
    const int w    = tid >> 6;
    const int lane = tid & 63;
    const int h    = lane >> 5;
    const int ql   = lane & 31;

    const int qblk = blockIdx.x & (NQB - 1);
    const int bh   = blockIdx.x / NQB;
    const int q0   = qblk * QBLK;
    const int qw   = q0 + w * 32;
    const int q    = qw + ql;

    const float* Qb = Qg + (size_t)bh * SEQ * DH;
    const float* Kb = Kg + (size_t)bh * SEQ * DH;
    const float* Vb = Vg + (size_t)bh * SEQ * DH;
    float*       Ob = Og + (size_t)bh * SEQ * DH;

    const float SC = 0.125f * 1.44269504f;

    const int skr  = tid >> 2;
    const int sd0  = (tid & 3) * 16;
    const int svk  = tid & 63;
    const int svd0 = (tid >> 6) * 16;

    bf16x8 qb[4];
    load_qfrags(Qb, q, h, SC, qb);

    f32x16 o0, o1;
    #pragma unroll
    for (int i = 0; i < 16; ++i) { o0[i] = 0.f; o1[i] = 0.f; }
    float m = -1e30f, lsum = 0.f;

    const int kend = qw + 32;
    const int nt   = (q0 + QBLK) / KBLK;

    for (int t = 0; t < nt; ++t) {
        const int kb = t * KBLK;
        __syncthreads();
        {
            const float* src = Kb + (size_t)(kb + skr) * DH + sd0;
            const float4 a0 = *reinterpret_cast<const float4*>(src);
            const float4 a1 = *reinterpret_cast<const float4*>(src + 4);
            const float4 a2 = *reinterpret_cast<const float4*>(src + 8);
            const float4 a3 = *reinterpret_cast<const float4*>(src + 12);
            V4U u0, u1;
            u0.w[0] = cvtpk(a0.x, a0.y); u0.w[1] = cvtpk(a0.z, a0.w);
            u0.w[2] = cvtpk(a1.x, a1.y); u0.w[3] = cvtpk(a1.z, a1.w);
            u1.w[0] = cvtpk(a2.x, a2.y); u1.w[1] = cvtpk(a2.z, a2.w);
            u1.w[2] = cvtpk(a3.x, a3.y); u1.w[3] = cvtpk(a3.z, a3.w);
            *reinterpret_cast<bf16x8*>(&Ks[swz(skr, sd0)])     = u0.v;
            *reinterpret_cast<bf16x8*>(&Ks[swz(skr, sd0 + 8)]) = u1.v;

            const float* vsrc = Vb + (size_t)(kb + svk) * DH + svd0;
            const float4 b0 = *reinterpret_cast<const float4*>(vsrc);
            const float4 b1 = *reinterpret_cast<const float4*>(vsrc + 4);
            const float4 b2 = *reinterpret_cast<const float4*>(vsrc + 8);
            const float4 b3 = *reinterpret_cast<const float4*>(vsrc + 12);
            const float vv[16] = {b0.x,b0.y,b0.z,b0.w, b1.x,b1.y,b1.z,b1.w,
                                  b2.x,b2.y,b2.z,b2.w, b3.x,b3.y,b3.z,b3.w};
            #pragma unroll
            for (int i = 0; i < 16; ++i)
                Vt[swz(svd0 + i, svk)] = bfbits(vv[i]);
        }
        __syncthreads();

        if (kb < kend) {
            const bool v2 = (kb + 32 < kend);
            f32x16 s0, s1;
            {
                bf16x8 kf[4];
                #pragma unroll
                for (int i = 0; i < 16; ++i) s0[i] = 0.f;
                #pragma unroll
                for (int dc = 0; dc < 4; ++dc)
                    kf[dc] = *reinterpret_cast<const bf16x8*>(&Ks[swz(ql, dc * 16 + h * 8)]);
                #pragma unroll
                for (int dc = 0; dc < 4; ++dc)
                    s0 = __builtin_amdgcn_mfma_f32_32x32x16_bf16(kf[dc], qb[dc], s0, 0, 0, 0);
                if (v2) {
                    #pragma unroll
                    for (int i = 0; i < 16; ++i) s1[i] = 0.f;
                    #pragma unroll
                    for (int dc = 0; dc < 4; ++dc)
                        kf[dc] = *reinterpret_cast<const bf16x8*>(&Ks[swz(32 + ql, dc * 16 + h * 8)]);
                    #pragma unroll
                    for (int dc = 0; dc < 4; ++dc)
                        s1 = __builtin_amdgcn_mfma_f32_32x32x16_bf16(kf[dc], qb[dc], s1, 0, 0, 0);
                }
            }
            bf16x8 pa[4];
            sm_pack(s0, s1, v2, kb, qw, q, h, m, lsum, o0, o1, pa);
            #pragma unroll
            for (int kt = 0; kt < 2; ++kt) {
                const bf16x8 vb0 = *reinterpret_cast<const bf16x8*>(&Vt[swz(ql,      kt * 16 + h * 8)]);
                const bf16x8 vb1 = *reinterpret_cast<const bf16x8*>(&Vt[swz(32 + ql, kt * 16 + h * 8)]);
                o0 = __builtin_amdgcn_mfma_f32_32x32x16_bf16(pa[kt], vb0, o0, 0, 0, 0);
                o1 = __builtin_amdgcn_mfma_f32_32x32x16_bf16(pa[kt], vb1, o1, 0, 0, 0);
            }
            if (v2) {
                #pragma unroll
                for (int kt = 2; kt < 4; ++kt) {
                    const bf16x8 vb0 = *reinterpret_cast<const bf16x8*>(&Vt[swz(ql,      kt * 16 + h * 8)]);
                    const bf16x8 vb1 = *reinterpret_cast<const bf16x8*>(&Vt[swz(32 + ql, kt * 16 + h * 8)]);
                    o0 = __builtin_amdgcn_mfma_f32_32x32x16_bf16(pa[kt], vb0, o0, 0, 0, 0);
                    o1 = __builtin_amdgcn_mfma_f32_32x32x16_bf16(pa[kt], vb1, o1, 0, 0, 0);
                }
            }
        }
    }

    epilogue_store(Ob, qw, h, ql, o0, o1, lsum);
}

extern "C" void kernel_launch(void* const* d_in, const int* in_sizes, int n_in,
                              void* d_out, int out_size, void* d_ws, size_t ws_size,
                              hipStream_t stream) {
    const float* Q = (const float*)d_in[0];
    const float* K = (const float*)d_in[1];
    const float* V = (const float*)d_in[2];
    // d_in[3] causal mask: synthesized in-kernel, not read.
    float* O = (float*)d_out;

    if (ws_size >= WS_NEEDED) {
        short* Kimg = (short*)d_ws;
        short* Vimg = Kimg + (size_t)64 * NTIL * 4096;
        prep_kv<<<dim3(64 * NTIL), 256, 0, stream>>>(K, V, Kimg, Vimg);
        attn_fwd<<<dim3(64 * 64), 64, 0, stream>>>(Q, Kimg, Vimg, O);
    } else {
        attn_fwd_fb<<<dim3(64 * NQB), 256, 0, stream>>>(Q, K, V, O);
    }
}